// Round 2
// baseline (3782.905 us; speedup 1.0000x reference)
//
#include <hip/hip_runtime.h>
#include <hip/hip_bf16.h>

// LCA layer on MI355X. b = x@W ; G = W^T W (diag zeroed, symmetric) ;
// u' = 0.9u + 0.1b - 0.1*relu(u-.1)@G  (9 fused steps; u1 = 0.1b analytic) ;
// out = relu(u-.1) @ W^T.
// GEMMs: m97-style 128x128 tile, bf16 MFMA 16x16x32, global_load_lds width-16,
// Bt ([N][K]) operand layout.  Workspace budget: 208 MiB (a/bb/u bf16 + W copies);
// xh and G live in d_out (dead before the final output GEMM writes it).

typedef __bf16 bf16_t;
typedef __bf16 bf16x8 __attribute__((ext_vector_type(8)));
typedef float  f32x4  __attribute__((ext_vector_type(4)));

__device__ __forceinline__ void g2lds16(const void* g, void* l) {
    __builtin_amdgcn_global_load_lds(
        (const __attribute__((address_space(1))) void*)g,
        (__attribute__((address_space(3))) void*)l,
        16, 0, 0);
}

enum { MODE_G = 0, MODE_B = 1, MODE_STEP = 2, MODE_OUT = 3 };

// C[m][n] = sum_k A[m][k] * Bt[n][k]   (A: [M][K], Bt: [N][K], bf16, K%32==0,
// grid covers M,N in 128-tiles). 256 thr = 4 waves 2x2, wave = 64x64 via 4x4 MFMA.
template<int MODE>
__global__ __launch_bounds__(256)
void gemm_bt(const bf16_t* __restrict__ A, const bf16_t* __restrict__ Bt,
             int N, int K,
             float*  __restrict__ outF,   // MODE_OUT: final fp32 output
             bf16_t* __restrict__ outH,   // MODE_G: G ; MODE_B: a
             bf16_t* __restrict__ bb,     // MODE_B: write b ; MODE_STEP: read b
             bf16_t* __restrict__ u)      // MODE_B: write u ; MODE_STEP: rmw u
{
    __shared__ __attribute__((aligned(16))) bf16_t As[128 * 32];
    __shared__ __attribute__((aligned(16))) bf16_t Bs[128 * 32];

    const int t  = threadIdx.x;
    const int l  = t & 63;
    const int w  = t >> 6;
    const int wm = (w >> 1) * 64;
    const int wn = (w & 1) * 64;

    const int rowA = blockIdx.y * 128;
    const int colB = blockIdx.x * 128;

    // staging: thread t loads 16B for rows t/4 and 64+t/4 at k-offset (t&3)*8
    const int srow = t >> 2;
    const int skc  = (t & 3) * 8;
    const bf16_t* gA = A  + (size_t)(rowA + srow) * K + skc;
    const bf16_t* gB = Bt + (size_t)(colB + srow) * K + skc;
    const size_t half = (size_t)64 * K;
    char* lA = (char*)As + t * 16;
    char* lB = (char*)Bs + t * 16;

    f32x4 acc[4][4];
#pragma unroll
    for (int i = 0; i < 4; ++i)
#pragma unroll
        for (int j = 0; j < 4; ++j)
#pragma unroll
            for (int r = 0; r < 4; ++r) acc[i][j][r] = 0.f;

    // A/B fragment: lane l -> row (l&15), k (l>>4)*8 .. +7 (16B contiguous)
    const int lrow = l & 15;
    const int lk   = (l >> 4) * 8;
    const bf16_t* pA = As + (wm + lrow) * 32 + lk;
    const bf16_t* pB = Bs + (wn + lrow) * 32 + lk;

    for (int k0 = 0; k0 < K; k0 += 32) {
        g2lds16(gA + k0,        lA);
        g2lds16(gA + half + k0, lA + 4096);
        g2lds16(gB + k0,        lB);
        g2lds16(gB + half + k0, lB + 4096);
        __syncthreads();   // vmcnt(0) drained before barrier -> LDS ready

        bf16x8 af[4], bfr[4];
#pragma unroll
        for (int i = 0; i < 4; ++i) af[i]  = *(const bf16x8*)(pA + i * 16 * 32);
#pragma unroll
        for (int j = 0; j < 4; ++j) bfr[j] = *(const bf16x8*)(pB + j * 16 * 32);
#pragma unroll
        for (int i = 0; i < 4; ++i)
#pragma unroll
            for (int j = 0; j < 4; ++j)
                acc[i][j] = __builtin_amdgcn_mfma_f32_16x16x32_bf16(
                    af[i], bfr[j], acc[i][j], 0, 0, 0);
        __syncthreads();
    }

    // epilogue. C/D layout: col = lane&15, row = (lane>>4)*4 + reg.
    const int r0 = rowA + wm + ((l >> 4) * 4);
    const int c0 = colB + wn + (l & 15);
#pragma unroll
    for (int i = 0; i < 4; ++i) {
#pragma unroll
        for (int j = 0; j < 4; ++j) {
#pragma unroll
            for (int r = 0; r < 4; ++r) {
                const int rg = r0 + i * 16 + r;
                const int cg = c0 + j * 16;
                const size_t idx = (size_t)rg * N + cg;
                const float c = acc[i][j][r];
                if (MODE == MODE_G) {
                    outH[idx] = (rg == cg) ? (bf16_t)0.f : (bf16_t)c;
                } else if (MODE == MODE_B) {
                    bb[idx] = (bf16_t)c;
                    const float un = 0.1f * c;          // u1 = 0.1*b (u0=0 => a0=0)
                    u[idx]  = (bf16_t)un;
                    outH[idx] = (bf16_t)fmaxf(un - 0.1f, 0.f);   // a1
                } else if (MODE == MODE_STEP) {
                    const float un = 0.9f * (float)u[idx]
                                   + 0.1f * (float)bb[idx] - 0.1f * c;
                    u[idx] = (bf16_t)un;                // write u only (no a race)
                } else { // MODE_OUT
                    outF[idx] = c;
                }
            }
        }
    }
}

__global__ void cast_x_kernel(const float* __restrict__ x, bf16_t* __restrict__ xh, int n) {
    int i = blockIdx.x * 256 + threadIdx.x;
    if (i < n) xh[i] = (bf16_t)x[i];
}

// Wh = bf16(W) [1024][4096] ; WT = bf16(W^T) [4096][1024]
__global__ void prep_w_kernel(const float* __restrict__ W,
                              bf16_t* __restrict__ Wh, bf16_t* __restrict__ WT) {
    int i = blockIdx.x * 256 + threadIdx.x;
    if (i < 1024 * 4096) {
        int k = i >> 12;
        int n = i & 4095;
        bf16_t v = (bf16_t)W[i];
        Wh[i] = v;
        WT[(size_t)n * 1024 + k] = v;
    }
}

// a = relu(u - 0.1), 8 bf16 per thread
__global__ void relu_a_kernel(const bf16x8* __restrict__ u, bf16x8* __restrict__ a, int nvec) {
    int i = blockIdx.x * 256 + threadIdx.x;
    if (i < nvec) {
        bf16x8 v = u[i];
        bf16x8 r;
#pragma unroll
        for (int j = 0; j < 8; ++j) r[j] = (bf16_t)fmaxf((float)v[j] - 0.1f, 0.f);
        a[i] = r;
    }
}

extern "C" void kernel_launch(void* const* d_in, const int* in_sizes, int n_in,
                              void* d_out, int out_size, void* d_ws, size_t ws_size,
                              hipStream_t stream)
{
    const float* x = (const float*)d_in[0];   // [8192][1024]
    const float* W = (const float*)d_in[1];   // [1024][4096]

    // d_out (32 MiB fp32) doubles as scratch until the final GEMM:
    bf16_t* xh = (bf16_t*)d_out;              // [8192][1024] bf16, 16 MiB (dead after b-GEMM)
    bf16_t* G  = (bf16_t*)d_out;              // [4096][4096] bf16, 32 MiB (written after b-GEMM)

    char* ws = (char*)d_ws;                   // 208 MiB total
    bf16_t* a  = (bf16_t*)(ws);               //  64 MiB [8192][4096]
    bf16_t* bb = (bf16_t*)(ws + 67108864);    //  64 MiB [8192][4096]
    bf16_t* u  = (bf16_t*)(ws + 134217728);   //  64 MiB [8192][4096]
    bf16_t* Wh = (bf16_t*)(ws + 201326592);   //   8 MiB [1024][4096]
    bf16_t* WT = (bf16_t*)(ws + 209715200);   //   8 MiB [4096][1024]

    cast_x_kernel<<<8388608 / 256, 256, 0, stream>>>(x, xh, 8388608);
    prep_w_kernel<<<4194304 / 256, 256, 0, stream>>>(W, Wh, WT);

    // b = x@W ; u1 = 0.1b ; a1 = relu(u1-0.1).  A = xh, Bt = WT, N=4096, K=1024
    gemm_bt<MODE_B><<<dim3(32, 64), 256, 0, stream>>>(xh, WT, 4096, 1024,
                                                      nullptr, a, bb, u);
    // G = W^T@W (diag=0) into d_out (xh now dead).  A = Bt = WT, N=4096, K=1024
    gemm_bt<MODE_G><<<dim3(32, 32), 256, 0, stream>>>(WT, WT, 4096, 1024,
                                                      nullptr, G, nullptr, nullptr);
    // 9 remaining steps: c = a@G (G symmetric => Bt = G); epilogue updates u;
    // then refresh a = relu(u-0.1).
    for (int s = 0; s < 9; ++s) {
        gemm_bt<MODE_STEP><<<dim3(32, 64), 256, 0, stream>>>(a, G, 4096, 4096,
                                                             nullptr, nullptr, bb, u);
        relu_a_kernel<<<4194304 / 256, 256, 0, stream>>>((const bf16x8*)u, (bf16x8*)a,
                                                         4194304);
    }
    // out = a @ W^T : A = a [8192][4096], Bt = Wh ([1024][4096]), N=1024, K=4096
    gemm_bt<MODE_OUT><<<dim3(8, 64), 256, 0, stream>>>(a, Wh, 1024, 4096,
                                                       (float*)d_out, nullptr, nullptr, nullptr);
}

// Round 3
// 2708.002 us; speedup vs baseline: 1.3969x; 1.3969x over previous
//
#include <hip/hip_runtime.h>
#include <hip/hip_bf16.h>

// LCA layer on MI355X — rank-factored steps.
//   b = x@W ; g[j] = sum_k W[k][j]^2
//   u1 = 0.1 b ; a1 = relu(u1 - 0.1)
//   per step: t = a@W^T (bf16) ; s = t@W ; u' = 0.9u + 0.1b - 0.1s + 0.1*a*g ;
//             a' = relu(u' - 0.1)          [a@G == a@(W^T W) - a*diag]
//   out = a@W^T (fp32)
// GEMM core: m97 structure — 128x128 tile, 4 waves 2x2, bf16 MFMA 16x16x32,
// global_load_lds width-16 staging, Bt ([N][K]) operand layout.

typedef __bf16 bf16_t;
typedef __bf16 bf16x8 __attribute__((ext_vector_type(8)));
typedef float  f32x4  __attribute__((ext_vector_type(4)));

__device__ __forceinline__ void g2lds16(const void* g, void* l) {
    __builtin_amdgcn_global_load_lds(
        (const __attribute__((address_space(1))) void*)g,
        (__attribute__((address_space(3))) void*)l,
        16, 0, 0);
}

enum { MODE_B = 0, MODE_T = 1, MODE_STEP2 = 2, MODE_OUT = 3 };

// C[m][n] = sum_k A[m][k] * Bt[n][k]  (A:[M][K], Bt:[N][K], bf16, K%32==0,
// grid covers M,N in 128-tiles). 256 thr = 4 waves 2x2; wave = 64x64 via 4x4 MFMA.
template<int MODE>
__global__ __launch_bounds__(256)
void gemm_bt(const bf16_t* __restrict__ A, const bf16_t* __restrict__ Bt,
             int N, int K,
             float*  __restrict__ outF,   // MODE_OUT: final fp32 output
             bf16_t* __restrict__ outH,   // MODE_T: t ; MODE_B/STEP2: a
             bf16_t* __restrict__ bb,     // MODE_B: write b ; MODE_STEP2: read b
             bf16_t* __restrict__ u,      // MODE_B: write u ; MODE_STEP2: rmw u
             const float* __restrict__ g) // MODE_STEP2: diag(W^T W), [N]
{
    __shared__ __attribute__((aligned(16))) bf16_t As[128 * 32];
    __shared__ __attribute__((aligned(16))) bf16_t Bs[128 * 32];

    const int t  = threadIdx.x;
    const int l  = t & 63;
    const int w  = t >> 6;
    const int wm = (w >> 1) * 64;
    const int wn = (w & 1) * 64;

    const int rowA = blockIdx.y * 128;
    const int colB = blockIdx.x * 128;

    // staging: thread t loads 16B for rows t/4 and 64+t/4 at k-offset (t&3)*8
    const int srow = t >> 2;
    const int skc  = (t & 3) * 8;
    const bf16_t* gA = A  + (size_t)(rowA + srow) * K + skc;
    const bf16_t* gB = Bt + (size_t)(colB + srow) * K + skc;
    const size_t half = (size_t)64 * K;
    char* lA = (char*)As + t * 16;
    char* lB = (char*)Bs + t * 16;

    f32x4 acc[4][4];
#pragma unroll
    for (int i = 0; i < 4; ++i)
#pragma unroll
        for (int j = 0; j < 4; ++j)
#pragma unroll
            for (int r = 0; r < 4; ++r) acc[i][j][r] = 0.f;

    // fragment read: lane l -> row (l&15), k (l>>4)*8 .. +7 (16B contiguous)
    const int lrow = l & 15;
    const int lk   = (l >> 4) * 8;
    const bf16_t* pA = As + (wm + lrow) * 32 + lk;
    const bf16_t* pB = Bs + (wn + lrow) * 32 + lk;

    for (int k0 = 0; k0 < K; k0 += 32) {
        g2lds16(gA + k0,        lA);
        g2lds16(gA + half + k0, lA + 4096);
        g2lds16(gB + k0,        lB);
        g2lds16(gB + half + k0, lB + 4096);
        __syncthreads();   // vmcnt(0) drained before barrier -> LDS ready

        bf16x8 af[4], bfr[4];
#pragma unroll
        for (int i = 0; i < 4; ++i) af[i]  = *(const bf16x8*)(pA + i * 16 * 32);
#pragma unroll
        for (int j = 0; j < 4; ++j) bfr[j] = *(const bf16x8*)(pB + j * 16 * 32);
#pragma unroll
        for (int i = 0; i < 4; ++i)
#pragma unroll
            for (int j = 0; j < 4; ++j)
                acc[i][j] = __builtin_amdgcn_mfma_f32_16x16x32_bf16(
                    af[i], bfr[j], acc[i][j], 0, 0, 0);
        __syncthreads();
    }

    // epilogue. C/D layout: col = lane&15, row = (lane>>4)*4 + reg.
    const int r0 = rowA + wm + ((l >> 4) * 4);
    const int c0 = colB + wn + (l & 15);

    float gv[4];
    if (MODE == MODE_STEP2) {
#pragma unroll
        for (int j = 0; j < 4; ++j) gv[j] = g[c0 + j * 16];
    }

#pragma unroll
    for (int i = 0; i < 4; ++i) {
#pragma unroll
        for (int j = 0; j < 4; ++j) {
#pragma unroll
            for (int r = 0; r < 4; ++r) {
                const int rg = r0 + i * 16 + r;
                const int cg = c0 + j * 16;
                const size_t idx = (size_t)rg * N + cg;
                const float c = acc[i][j][r];
                if (MODE == MODE_T) {
                    outH[idx] = (bf16_t)c;                       // t = a@W^T
                } else if (MODE == MODE_B) {
                    bb[idx] = (bf16_t)c;
                    const float un = 0.1f * c;                   // u1 = 0.1 b
                    u[idx]  = (bf16_t)un;
                    outH[idx] = (bf16_t)fmaxf(un - 0.1f, 0.f);   // a1
                } else if (MODE == MODE_STEP2) {
                    const float uo = (float)u[idx];
                    const float ao = fmaxf(uo - 0.1f, 0.f);      // a_old from u_old
                    const float un = 0.9f * uo + 0.1f * (float)bb[idx]
                                   - 0.1f * c + 0.1f * ao * gv[j];
                    u[idx]  = (bf16_t)un;
                    outH[idx] = (bf16_t)fmaxf(un - 0.1f, 0.f);   // a_next (no race:
                                                                 // a is not an operand here)
                } else { // MODE_OUT
                    outF[idx] = c;
                }
            }
        }
    }
}

__global__ void cast_x_kernel(const float* __restrict__ x, bf16_t* __restrict__ xh, int n) {
    int i = blockIdx.x * 256 + threadIdx.x;
    if (i < n) xh[i] = (bf16_t)x[i];
}

// Wh = bf16(W) [1024][4096] ; WT = bf16(W^T) [4096][1024]
__global__ void prep_w_kernel(const float* __restrict__ W,
                              bf16_t* __restrict__ Wh, bf16_t* __restrict__ WT) {
    int i = blockIdx.x * 256 + threadIdx.x;
    if (i < 1024 * 4096) {
        int k = i >> 12;
        int n = i & 4095;
        bf16_t v = (bf16_t)W[i];
        Wh[i] = v;
        WT[(size_t)n * 1024 + k] = v;
    }
}

// g[j] = sum_k W[k][j]^2  (fp32 W, coalesced across threads)
__global__ void prep_g_kernel(const float* __restrict__ W, float* __restrict__ g) {
    int j = blockIdx.x * 256 + threadIdx.x;
    if (j < 4096) {
        float s = 0.f;
        for (int k = 0; k < 1024; ++k) {
            float v = W[(size_t)k * 4096 + j];
            s += v * v;
        }
        g[j] = s;
    }
}

extern "C" void kernel_launch(void* const* d_in, const int* in_sizes, int n_in,
                              void* d_out, int out_size, void* d_ws, size_t ws_size,
                              hipStream_t stream)
{
    const float* x = (const float*)d_in[0];   // [8192][1024]
    const float* W = (const float*)d_in[1];   // [1024][4096]

    // d_out (32 MiB fp32) doubles as scratch until the final GEMM writes it:
    //   [0,16MiB):  xh (bf16 x) until b-GEMM, then t (bf16 [8192][1024])
    //   [16MiB,16MiB+16KiB): g (fp32 [4096])
    bf16_t* xh = (bf16_t*)d_out;
    bf16_t* tt = (bf16_t*)d_out;
    float*  gd = (float*)((char*)d_out + 16777216);

    char* ws = (char*)d_ws;                   // 208 MiB total (proven footprint)
    bf16_t* a  = (bf16_t*)(ws);               //  64 MiB [8192][4096]
    bf16_t* bb = (bf16_t*)(ws + 67108864);    //  64 MiB [8192][4096]
    bf16_t* u  = (bf16_t*)(ws + 134217728);   //  64 MiB [8192][4096]
    bf16_t* Wh = (bf16_t*)(ws + 201326592);   //   8 MiB [1024][4096]
    bf16_t* WT = (bf16_t*)(ws + 209715200);   //   8 MiB [4096][1024]

    cast_x_kernel<<<8388608 / 256, 256, 0, stream>>>(x, xh, 8388608);
    prep_w_kernel<<<4194304 / 256, 256, 0, stream>>>(W, Wh, WT);
    prep_g_kernel<<<16, 256, 0, stream>>>(W, gd);

    // b = x@W ; u1 = 0.1b ; a1 = relu(u1-0.1).  A=xh, Bt=WT, N=4096, K=1024
    gemm_bt<MODE_B><<<dim3(32, 64), 256, 0, stream>>>(xh, WT, 4096, 1024,
                                                      nullptr, a, bb, u, nullptr);
    // 9 remaining steps, rank-factored:
    //   t = a@W^T   (A=a, Bt=Wh, N=1024, K=4096)   -> t in d_out (xh dead)
    //   s = t@W     (A=t, Bt=WT, N=4096, K=1024)   -> fused u update + a_next
    for (int s = 0; s < 9; ++s) {
        gemm_bt<MODE_T><<<dim3(8, 64), 256, 0, stream>>>(a, Wh, 1024, 4096,
                                                         nullptr, tt, nullptr, nullptr, nullptr);
        gemm_bt<MODE_STEP2><<<dim3(32, 64), 256, 0, stream>>>(tt, WT, 4096, 1024,
                                                              nullptr, a, bb, u, gd);
    }
    // out = a@W^T : A=a, Bt=Wh, N=1024, K=4096, fp32 into d_out
    gemm_bt<MODE_OUT><<<dim3(8, 64), 256, 0, stream>>>(a, Wh, 1024, 4096,
                                                       (float*)d_out, nullptr, nullptr, nullptr, nullptr);
}

// Round 4
// 2367.962 us; speedup vs baseline: 1.5975x; 1.1436x over previous
//
#include <hip/hip_runtime.h>
#include <hip/hip_bf16.h>

// LCA layer on MI355X — rank-factored steps, vectorized epilogue.
//   b = x@W ; g[j] = sum_k W[k][j]^2
//   u1 = 0.1 b ; a1 = relu(u1 - 0.1)
//   per step: t = a@W^T ; s = t@W ; u' = 0.9u + 0.1b - 0.1s + 0.1*a*g ; a' = relu(u'-0.1)
//   out = a@W^T (fp32)
// GEMM core: 128x128 tile, 4 waves 2x2, bf16 MFMA 16x16x32 with OPERAND SWAP
// (lane's 4 acc regs = 4 consecutive output cols at one row -> 8B/16B vector
// epilogue), BK=64 as two BK=32 LDS planes (same staging pattern as m97),
// global_load_lds width-16, Bt ([N][K]) operand layout.

typedef __bf16 bf16_t;
typedef __bf16 bf16x8 __attribute__((ext_vector_type(8)));
typedef __bf16 bf16x4 __attribute__((ext_vector_type(4)));
typedef float  f32x4  __attribute__((ext_vector_type(4)));

__device__ __forceinline__ void g2lds16(const void* g, void* l) {
    __builtin_amdgcn_global_load_lds(
        (const __attribute__((address_space(1))) void*)g,
        (__attribute__((address_space(3))) void*)l,
        16, 0, 0);
}

enum { MODE_B = 0, MODE_T = 1, MODE_STEP2 = 2, MODE_OUT = 3 };

// C[m][n] = sum_k A[m][k] * Bt[n][k]  (A:[M][K], Bt:[N][K], bf16, K%64==0,
// grid covers M,N in 128-tiles). 256 thr = 4 waves 2x2; wave = 64x64 via 4x4 MFMA.
template<int MODE>
__global__ __launch_bounds__(256)
void gemm_bt(const bf16_t* __restrict__ A, const bf16_t* __restrict__ Bt,
             int N, int K,
             float*  __restrict__ outF,   // MODE_OUT: final fp32 output
             bf16_t* __restrict__ outH,   // MODE_T: t ; MODE_B/STEP2: a
             bf16_t* __restrict__ bb,     // MODE_B: write b ; MODE_STEP2: read b
             bf16_t* __restrict__ u,      // MODE_B: write u ; MODE_STEP2: rmw u
             const float* __restrict__ g) // MODE_STEP2: diag(W^T W), [N]
{
    // two BK=32 planes per operand: As[2][128][32], Bs[2][128][32]
    __shared__ __attribute__((aligned(16))) bf16_t As[2 * 128 * 32];
    __shared__ __attribute__((aligned(16))) bf16_t Bs[2 * 128 * 32];

    const int t  = threadIdx.x;
    const int l  = t & 63;
    const int w  = t >> 6;
    const int wm = (w >> 1) * 64;
    const int wn = (w & 1) * 64;

    const int rowA = blockIdx.y * 128;
    const int colB = blockIdx.x * 128;

    // staging (per plane identical to m97 BK=32): thread t loads 16B for rows
    // t/4 and 64+t/4 at k-offset (t&3)*8 within the plane.
    const int srow = t >> 2;
    const int skc  = (t & 3) * 8;
    const bf16_t* gA = A  + (size_t)(rowA + srow) * K + skc;
    const bf16_t* gB = Bt + (size_t)(colB + srow) * K + skc;
    const size_t half = (size_t)64 * K;
    char* lA = (char*)As + t * 16;
    char* lB = (char*)Bs + t * 16;

    f32x4 acc[4][4];
#pragma unroll
    for (int i = 0; i < 4; ++i)
#pragma unroll
        for (int j = 0; j < 4; ++j)
#pragma unroll
            for (int r = 0; r < 4; ++r) acc[i][j][r] = 0.f;

    // fragment read: lane l -> index (l&15), k (l>>4)*8 .. +7 (16B contiguous)
    const int lrow = l & 15;
    const int lk   = (l >> 4) * 8;
    const bf16_t* pA = As + (wm + lrow) * 32 + lk;
    const bf16_t* pB = Bs + (wn + lrow) * 32 + lk;

    for (int k0 = 0; k0 < K; k0 += 64) {
        // plane 0 = k0..k0+31, plane 1 = k0+32..k0+63
        g2lds16(gA + k0,             lA);
        g2lds16(gA + k0 + half,      lA + 4096);
        g2lds16(gA + k0 + 32,        lA + 8192);
        g2lds16(gA + k0 + 32 + half, lA + 12288);
        g2lds16(gB + k0,             lB);
        g2lds16(gB + k0 + half,      lB + 4096);
        g2lds16(gB + k0 + 32,        lB + 8192);
        g2lds16(gB + k0 + 32 + half, lB + 12288);
        __syncthreads();   // vmcnt(0) drained before barrier -> LDS ready

#pragma unroll
        for (int p = 0; p < 2; ++p) {
            const bf16_t* qA = pA + p * 4096;
            const bf16_t* qB = pB + p * 4096;
            bf16x8 af[4], bfr[4];
#pragma unroll
            for (int i = 0; i < 4; ++i) af[i]  = *(const bf16x8*)(qA + i * 16 * 32);
#pragma unroll
            for (int j = 0; j < 4; ++j) bfr[j] = *(const bf16x8*)(qB + j * 16 * 32);
            // OPERAND SWAP: pass (b_frag, a_frag) -> lane holds
            // C[m = wm+i*16+(l&15)][n = wn+j*16+(l>>4)*4 + r], r = 0..3 contiguous.
#pragma unroll
            for (int i = 0; i < 4; ++i)
#pragma unroll
                for (int j = 0; j < 4; ++j)
                    acc[i][j] = __builtin_amdgcn_mfma_f32_16x16x32_bf16(
                        bfr[j], af[i], acc[i][j], 0, 0, 0);
        }
        __syncthreads();
    }

    // epilogue (swapped layout): m = rowA+wm+i*16+(l&15), n = colB+wn+j*16+(l>>4)*4+r
    const int m0 = rowA + wm + (l & 15);
    const int n0 = colB + wn + ((l >> 4) * 4);

    f32x4 gvv[4];
    if (MODE == MODE_STEP2) {
#pragma unroll
        for (int j = 0; j < 4; ++j) gvv[j] = *(const f32x4*)(g + n0 + j * 16);
    }

#pragma unroll
    for (int i = 0; i < 4; ++i) {
        const int m = m0 + i * 16;
#pragma unroll
        for (int j = 0; j < 4; ++j) {
            const size_t idx = (size_t)m * N + (n0 + j * 16);
            const f32x4 c = acc[i][j];
            if (MODE == MODE_T) {
                bf16x4 o;
#pragma unroll
                for (int r = 0; r < 4; ++r) o[r] = (bf16_t)c[r];
                *(bf16x4*)(outH + idx) = o;
            } else if (MODE == MODE_B) {
                bf16x4 ob, ou, oa;
#pragma unroll
                for (int r = 0; r < 4; ++r) {
                    const float un = 0.1f * c[r];       // u1 = 0.1 b (u0=0 => a0=0)
                    ob[r] = (bf16_t)c[r];
                    ou[r] = (bf16_t)un;
                    oa[r] = (bf16_t)fmaxf(un - 0.1f, 0.f);
                }
                *(bf16x4*)(bb   + idx) = ob;
                *(bf16x4*)(u    + idx) = ou;
                *(bf16x4*)(outH + idx) = oa;
            } else if (MODE == MODE_STEP2) {
                const bf16x4 uv = *(const bf16x4*)(u  + idx);
                const bf16x4 bv = *(const bf16x4*)(bb + idx);
                bf16x4 ou, oa;
#pragma unroll
                for (int r = 0; r < 4; ++r) {
                    const float uo = (float)uv[r];
                    const float ao = fmaxf(uo - 0.1f, 0.f);    // a_old from u_old
                    const float un = 0.9f * uo + 0.1f * (float)bv[r]
                                   - 0.1f * c[r] + 0.1f * ao * gvv[j][r];
                    ou[r] = (bf16_t)un;
                    oa[r] = (bf16_t)fmaxf(un - 0.1f, 0.f);     // a_next (no race)
                }
                *(bf16x4*)(u    + idx) = ou;
                *(bf16x4*)(outH + idx) = oa;
            } else { // MODE_OUT
                *(f32x4*)(outF + idx) = c;
            }
        }
    }
}

__global__ void cast_x_kernel(const float* __restrict__ x, bf16_t* __restrict__ xh, int n) {
    int i = blockIdx.x * 256 + threadIdx.x;
    if (i < n) xh[i] = (bf16_t)x[i];
}

// Wh = bf16(W) [1024][4096] ; WT = bf16(W^T) [4096][1024]
__global__ void prep_w_kernel(const float* __restrict__ W,
                              bf16_t* __restrict__ Wh, bf16_t* __restrict__ WT) {
    int i = blockIdx.x * 256 + threadIdx.x;
    if (i < 1024 * 4096) {
        int k = i >> 12;
        int n = i & 4095;
        bf16_t v = (bf16_t)W[i];
        Wh[i] = v;
        WT[(size_t)n * 1024 + k] = v;
    }
}

// g[j] = sum_k W[k][j]^2
__global__ void prep_g_kernel(const float* __restrict__ W, float* __restrict__ g) {
    int j = blockIdx.x * 256 + threadIdx.x;
    if (j < 4096) {
        float s = 0.f;
        for (int k = 0; k < 1024; ++k) {
            float v = W[(size_t)k * 4096 + j];
            s += v * v;
        }
        g[j] = s;
    }
}

extern "C" void kernel_launch(void* const* d_in, const int* in_sizes, int n_in,
                              void* d_out, int out_size, void* d_ws, size_t ws_size,
                              hipStream_t stream)
{
    const float* x = (const float*)d_in[0];   // [8192][1024]
    const float* W = (const float*)d_in[1];   // [1024][4096]

    // d_out doubles as scratch until the final GEMM writes it:
    //   [0,16MiB): xh (bf16 x) until b-GEMM, then t ; [16MiB,+16KiB): g
    bf16_t* xh = (bf16_t*)d_out;
    bf16_t* tt = (bf16_t*)d_out;
    float*  gd = (float*)((char*)d_out + 16777216);

    char* ws = (char*)d_ws;                   // 208 MiB total (proven footprint)
    bf16_t* a  = (bf16_t*)(ws);               //  64 MiB [8192][4096]
    bf16_t* bb = (bf16_t*)(ws + 67108864);    //  64 MiB [8192][4096]
    bf16_t* u  = (bf16_t*)(ws + 134217728);   //  64 MiB [8192][4096]
    bf16_t* Wh = (bf16_t*)(ws + 201326592);   //   8 MiB [1024][4096]
    bf16_t* WT = (bf16_t*)(ws + 209715200);   //   8 MiB [4096][1024]

    cast_x_kernel<<<8388608 / 256, 256, 0, stream>>>(x, xh, 8388608);
    prep_w_kernel<<<4194304 / 256, 256, 0, stream>>>(W, Wh, WT);
    prep_g_kernel<<<16, 256, 0, stream>>>(W, gd);

    // b = x@W ; u1 = 0.1b ; a1 = relu(u1-0.1).  A=xh, Bt=WT, N=4096, K=1024
    gemm_bt<MODE_B><<<dim3(32, 64), 256, 0, stream>>>(xh, WT, 4096, 1024,
                                                      nullptr, a, bb, u, nullptr);
    // 9 remaining steps: t = a@W^T (N=1024,K=4096) ; s = t@W fused u/a update
    for (int s = 0; s < 9; ++s) {
        gemm_bt<MODE_T><<<dim3(8, 64), 256, 0, stream>>>(a, Wh, 1024, 4096,
                                                         nullptr, tt, nullptr, nullptr, nullptr);
        gemm_bt<MODE_STEP2><<<dim3(32, 64), 256, 0, stream>>>(tt, WT, 4096, 1024,
                                                              nullptr, a, bb, u, gd);
    }
    // out = a@W^T : A=a, Bt=Wh, N=1024, K=4096, fp32 into d_out
    gemm_bt<MODE_OUT><<<dim3(8, 64), 256, 0, stream>>>(a, Wh, 1024, 4096,
                                                       (float*)d_out, nullptr, nullptr, nullptr, nullptr);
}